// Round 2
// baseline (705.238 us; speedup 1.0000x reference)
//
#include <hip/hip_runtime.h>

// ---------------- CSR build ----------------

__global__ __launch_bounds__(256) void k_hist(const int* __restrict__ dst, int E,
                                              int* __restrict__ degcnt) {
    int i = blockIdx.x * 256 + threadIdx.x;
    if (i < E) atomicAdd(&degcnt[dst[i]], 1);
}

__global__ __launch_bounds__(256) void k_deg_finalize(const int* __restrict__ degcnt,
                                                      float* __restrict__ invsqrt,
                                                      int* __restrict__ blocksums, int N) {
    __shared__ int sd[256];
    int t = threadIdx.x;
    int i = blockIdx.x * 256 + t;
    int v = (i < N) ? degcnt[i] : 0;
    if (i < N) invsqrt[i] = rsqrtf((float)(v + 1));   // +1: self-loop
    sd[t] = v;
    __syncthreads();
#pragma unroll
    for (int s = 128; s > 0; s >>= 1) {
        if (t < s) sd[t] += sd[t + s];
        __syncthreads();
    }
    if (t == 0) blocksums[blockIdx.x] = sd[0];
}

__global__ __launch_bounds__(1024) void k_scan_blocks(int* blocksums, int NB) {
    __shared__ int s[1024];
    int t = threadIdx.x;
    int v = (t < NB) ? blocksums[t] : 0;
    s[t] = v;
    __syncthreads();
    for (int off = 1; off < 1024; off <<= 1) {
        int x = (t >= off) ? s[t - off] : 0;
        __syncthreads();
        s[t] += x;
        __syncthreads();
    }
    if (t < NB) blocksums[t] = s[t] - v;   // exclusive
}

__global__ __launch_bounds__(256) void k_rowstart(const int* __restrict__ degcnt,
                                                  const int* __restrict__ blocksums,
                                                  int* __restrict__ rowstart,
                                                  int* __restrict__ rowwork, int N, int E) {
    __shared__ int s[256];
    int t = threadIdx.x;
    int i = blockIdx.x * 256 + t;
    int v = (i < N) ? degcnt[i] : 0;
    s[t] = v;
    __syncthreads();
    for (int off = 1; off < 256; off <<= 1) {
        int x = (t >= off) ? s[t - off] : 0;
        __syncthreads();
        s[t] += x;
        __syncthreads();
    }
    if (i < N) {
        int e = s[t] - v + blocksums[blockIdx.x];
        rowstart[i] = e;
        rowwork[i] = e;
    }
    if (blockIdx.x == 0 && t == 0) rowstart[N] = E;
}

__global__ __launch_bounds__(256) void k_fill(const int* __restrict__ src,
                                              const int* __restrict__ dst, int E,
                                              const float* __restrict__ invsqrt,
                                              int* __restrict__ rowwork,
                                              int* __restrict__ csr_src,
                                              float* __restrict__ csr_w) {
    int i = blockIdx.x * 256 + threadIdx.x;
    if (i < E) {
        int s = src[i], d = dst[i];
        int pos = atomicAdd(&rowwork[d], 1);
        csr_src[pos] = s;
        csr_w[pos] = invsqrt[s];
    }
}

// ---------------- GEMM1: x[N,256] @ W[256,128] -> out[N,128] ----------------

__global__ __launch_bounds__(256) void k_gemm1(const float* __restrict__ x,
                                               const float* __restrict__ W,
                                               float* __restrict__ out, int N) {
    __shared__ __align__(16) float xs[64][36];
    __shared__ __align__(16) float ws[32][128];
    int t = threadIdx.x;
    int c = t & 31;    // col group: cols c*4..c*4+3
    int r = t >> 5;    // row group: rows r, r+8, ..., r+56
    int row0 = blockIdx.x * 64;
    float acc[8][4];
#pragma unroll
    for (int a = 0; a < 8; a++)
#pragma unroll
        for (int b = 0; b < 4; b++) acc[a][b] = 0.f;

    for (int k0 = 0; k0 < 256; k0 += 32) {
#pragma unroll
        for (int l = 0; l < 2; l++) {
            int idx = t + 256 * l;
            int rr = idx >> 3, kq = idx & 7;
            int grow = row0 + rr;
            float4 v = make_float4(0.f, 0.f, 0.f, 0.f);
            if (grow < N) v = *(const float4*)(x + (size_t)grow * 256 + k0 + kq * 4);
            *(float4*)&xs[rr][kq * 4] = v;
        }
#pragma unroll
        for (int l = 0; l < 4; l++) {
            int idx = t + 256 * l;
            int kr = idx >> 5, cq = idx & 31;
            *(float4*)&ws[kr][cq * 4] = *(const float4*)(W + (size_t)(k0 + kr) * 128 + cq * 4);
        }
        __syncthreads();
#pragma unroll
        for (int kk = 0; kk < 32; kk++) {
            float4 wv = *(float4*)&ws[kk][c * 4];
#pragma unroll
            for (int rr = 0; rr < 8; rr++) {
                float xv = xs[r + 8 * rr][kk];
                acc[rr][0] = fmaf(xv, wv.x, acc[rr][0]);
                acc[rr][1] = fmaf(xv, wv.y, acc[rr][1]);
                acc[rr][2] = fmaf(xv, wv.z, acc[rr][2]);
                acc[rr][3] = fmaf(xv, wv.w, acc[rr][3]);
            }
        }
        __syncthreads();
    }
#pragma unroll
    for (int rr = 0; rr < 8; rr++) {
        int grow = row0 + r + 8 * rr;
        if (grow < N) {
            float4 v = make_float4(acc[rr][0], acc[rr][1], acc[rr][2], acc[rr][3]);
            *(float4*)(out + (size_t)grow * 128 + c * 4) = v;
        }
    }
}

// ---------------- GEMM2: G[N,128] @ [Wmu|Wls][128,128] + bias -> mu, ls ----------------

__global__ __launch_bounds__(256) void k_gemm2(const float* __restrict__ G,
                                               const float* __restrict__ Wmu,
                                               const float* __restrict__ bmu,
                                               const float* __restrict__ Wls,
                                               const float* __restrict__ bls,
                                               float* __restrict__ omu,
                                               float* __restrict__ ols, int N) {
    __shared__ __align__(16) float xs[64][36];
    __shared__ __align__(16) float ws[32][128];
    int t = threadIdx.x;
    int c = t & 31;
    int r = t >> 5;
    int row0 = blockIdx.x * 64;
    float acc[8][4];
#pragma unroll
    for (int a = 0; a < 8; a++)
#pragma unroll
        for (int b = 0; b < 4; b++) acc[a][b] = 0.f;

    for (int k0 = 0; k0 < 128; k0 += 32) {
#pragma unroll
        for (int l = 0; l < 2; l++) {
            int idx = t + 256 * l;
            int rr = idx >> 3, kq = idx & 7;
            int grow = row0 + rr;
            float4 v = make_float4(0.f, 0.f, 0.f, 0.f);
            if (grow < N) v = *(const float4*)(G + (size_t)grow * 128 + k0 + kq * 4);
            *(float4*)&xs[rr][kq * 4] = v;
        }
#pragma unroll
        for (int l = 0; l < 4; l++) {
            int idx = t + 256 * l;
            int kr = idx >> 5, cq = idx & 31;
            const float* wp = (cq < 16) ? (Wmu + (size_t)(k0 + kr) * 64 + cq * 4)
                                        : (Wls + (size_t)(k0 + kr) * 64 + (cq - 16) * 4);
            *(float4*)&ws[kr][cq * 4] = *(const float4*)wp;
        }
        __syncthreads();
#pragma unroll
        for (int kk = 0; kk < 32; kk++) {
            float4 wv = *(float4*)&ws[kk][c * 4];
#pragma unroll
            for (int rr = 0; rr < 8; rr++) {
                float xv = xs[r + 8 * rr][kk];
                acc[rr][0] = fmaf(xv, wv.x, acc[rr][0]);
                acc[rr][1] = fmaf(xv, wv.y, acc[rr][1]);
                acc[rr][2] = fmaf(xv, wv.z, acc[rr][2]);
                acc[rr][3] = fmaf(xv, wv.w, acc[rr][3]);
            }
        }
        __syncthreads();
    }
    const float* bp = (c < 16) ? (bmu + c * 4) : (bls + (c - 16) * 4);
    float4 bv = *(const float4*)bp;
    float* ob = (c < 16) ? omu : ols;
    int ccol = (c < 16) ? c * 4 : (c - 16) * 4;
#pragma unroll
    for (int rr = 0; rr < 8; rr++) {
        int grow = row0 + r + 8 * rr;
        if (grow < N) {
            float4 v = make_float4(acc[rr][0] + bv.x, acc[rr][1] + bv.y,
                                   acc[rr][2] + bv.z, acc[rr][3] + bv.w);
            *(float4*)(ob + (size_t)grow * 64 + ccol) = v;
        }
    }
}

// ---------------- Aggregation: out[i] = isq_i*(sum_e w_e*in[s_e] + isq_i*in[i]) ----------------

template <int RELU>
__global__ __launch_bounds__(128) void k_agg(const float* __restrict__ in,
                                             const float* __restrict__ invsqrt,
                                             const int* __restrict__ rowstart,
                                             const int* __restrict__ csr_src,
                                             const float* __restrict__ csr_w,
                                             const float* __restrict__ bias,
                                             float* __restrict__ out, int N) {
    int i = blockIdx.x;
    int f = threadIdx.x;   // feature 0..127
    __shared__ int s_src[128];
    __shared__ float s_w[128];
    int start = rowstart[i], end = rowstart[i + 1];
    float isq = invsqrt[i];
    float acc = isq * in[(size_t)i * 128 + f];   // self-loop term (norm = isq^2, outer isq applied at end)
    for (int base = start; base < end; base += 128) {
        int cnt = min(128, end - base);
        if (f < cnt) {
            s_src[f] = csr_src[base + f];
            s_w[f] = csr_w[base + f];
        }
        __syncthreads();
        int j = 0;
        for (; j + 4 <= cnt; j += 4) {
            int s0 = s_src[j], s1 = s_src[j + 1], s2 = s_src[j + 2], s3 = s_src[j + 3];
            float w0 = s_w[j], w1 = s_w[j + 1], w2 = s_w[j + 2], w3 = s_w[j + 3];
            float a0 = in[(size_t)s0 * 128 + f];
            float a1 = in[(size_t)s1 * 128 + f];
            float a2 = in[(size_t)s2 * 128 + f];
            float a3 = in[(size_t)s3 * 128 + f];
            acc = fmaf(w0, a0, acc);
            acc = fmaf(w1, a1, acc);
            acc = fmaf(w2, a2, acc);
            acc = fmaf(w3, a3, acc);
        }
        for (; j < cnt; j++) acc = fmaf(s_w[j], in[(size_t)s_src[j] * 128 + f], acc);
        __syncthreads();
    }
    float rv = isq * acc;
    if (RELU) {
        rv += bias[f];
        rv = fmaxf(rv, 0.f);
    }
    out[(size_t)i * 128 + f] = rv;
}

// ---------------- launch ----------------

extern "C" void kernel_launch(void* const* d_in, const int* in_sizes, int n_in,
                              void* d_out, int out_size, void* d_ws, size_t ws_size,
                              hipStream_t stream) {
    const float* x   = (const float*)d_in[0];
    const int*   ei  = (const int*)d_in[1];
    const float* W1  = (const float*)d_in[2];
    const float* b1  = (const float*)d_in[3];
    const float* Wmu = (const float*)d_in[4];
    const float* bmu = (const float*)d_in[5];
    const float* Wls = (const float*)d_in[6];
    const float* bls = (const float*)d_in[7];

    int N = in_sizes[0] / 256;
    int E = in_sizes[1] / 2;
    const int* src = ei;
    const int* dst = ei + E;
    float* omu = (float*)d_out;
    float* ols = omu + (size_t)N * 64;

    char* w = (char*)d_ws;
    size_t off = 0;
    auto alloc = [&](size_t bytes) -> char* {
        char* p = w + off;
        off = (off + bytes + 255) & ~(size_t)255;
        return p;
    };
    int*   degcnt    = (int*)alloc((size_t)N * 4);
    float* invsqrt   = (float*)alloc((size_t)N * 4);
    int*   rowstart  = (int*)alloc((size_t)(N + 1) * 4);
    int*   rowwork   = (int*)alloc((size_t)N * 4);
    int*   blocksums = (int*)alloc(4096);
    int*   csr_src   = (int*)alloc((size_t)E * 4);
    float* csr_w     = (float*)alloc((size_t)E * 4);
    float* bufA      = (float*)alloc((size_t)N * 128 * 4);   // H1, later G2
    float* bufB      = (float*)alloc((size_t)N * 128 * 4);   // h = relu(...)

    int NB = (N + 255) / 256;

    hipMemsetAsync(degcnt, 0, (size_t)N * 4, stream);
    k_hist<<<(E + 255) / 256, 256, 0, stream>>>(dst, E, degcnt);
    k_deg_finalize<<<NB, 256, 0, stream>>>(degcnt, invsqrt, blocksums, N);
    k_scan_blocks<<<1, 1024, 0, stream>>>(blocksums, NB);
    k_rowstart<<<NB, 256, 0, stream>>>(degcnt, blocksums, rowstart, rowwork, N, E);
    k_fill<<<(E + 255) / 256, 256, 0, stream>>>(src, dst, E, invsqrt, rowwork, csr_src, csr_w);

    k_gemm1<<<(N + 63) / 64, 256, 0, stream>>>(x, W1, bufA, N);
    k_agg<1><<<N, 128, 0, stream>>>(bufA, invsqrt, rowstart, csr_src, csr_w, b1, bufB, N);
    k_agg<0><<<N, 128, 0, stream>>>(bufB, invsqrt, rowstart, csr_src, csr_w, nullptr, bufA, N);
    k_gemm2<<<(N + 63) / 64, 256, 0, stream>>>(bufA, Wmu, bmu, Wls, bls, omu, ols, N);
}